// Round 5
// baseline (34.456 us; speedup 1.0000x reference)
//
#include <hip/hip_runtime.h>
#include <math.h>

#define B  16
#define LQ 256
#define LC 256
#define D  64
#define QT 4
#define TS   2.88539008177793f    // 2*log2(e)
#define L2E  1.44269504088896f    // log2(e)
#define PAD  72                   // LDS row stride (floats) for w_t [k][64]
#define INPAD 36                  // LDS row stride for in_t [k][32]
#define TPAD 33                   // LDS row stride for transpose tile [e][32]
#define CP4  264                  // esct pitch in float4 units (4224B, non-pow2)

// ---------------------------------------------------------------------------
// bank_proj_kernel: BANK-side projections only (query side fused into attn).
//  256 blocks = 2 types x 128 row-blocks, R2-proven LDS GEMM structure.
//   tp 1: esct4[b,d4,c] = float4(exp2(TS*(Wc[4d4+j,:].bank[b,c,:]+bc)), j=0..3)
//   tp 3: wb  [r,e]     = Woc[e,:] . bank[r,:] + boc[e]              row-major
//  XCD-ALIGNED row-chunk remap: chunk for batch bb lands on block id%8 == bb%8,
//  matching attn_kernel's batch->XCD pin.
// ---------------------------------------------------------------------------
__global__ __launch_bounds__(256) void bank_proj_kernel(
    const float* __restrict__ bank,
    const float* __restrict__ Wc, const float* __restrict__ bc,
    const float* __restrict__ Woc, const float* __restrict__ boc,
    float* __restrict__ esct, float* __restrict__ wb)
{
    int t  = threadIdx.x;
    int tp1 = (blockIdx.x >> 7) == 0;                // blocks 0..127: esct
    int rb = blockIdx.x & 127;
    // batch-aligned remap: bb = (rb&7)+8*(rb>>6) in [0,16), j = (rb>>3)&7
    int bb_x = (rb & 7) + ((rb >> 6) << 3);
    int jj   = (rb >> 3) & 7;
    int r0 = bb_x * 256 + jj * 32;

    __shared__ __align__(16) float in_t[64 * INPAD]; // [k][32]
    __shared__ __align__(16) float w_t [64 * PAD];   // [k][64]
    __shared__ float tr[64 * TPAD];                  // [e][32], tp1 only

    const float* W = tp1 ? Wc : Woc;

    #pragma unroll
    for (int it = 0; it < 2; ++it) {
        int g = it * 256 + t;
        int kc4 = g & 15, row = g >> 4;              // row 0..31
        float4 v = *reinterpret_cast<const float4*>(bank + (r0 + row) * D + kc4 * 4);
        in_t[(kc4*4+0)*INPAD + row] = v.x; in_t[(kc4*4+1)*INPAD + row] = v.y;
        in_t[(kc4*4+2)*INPAD + row] = v.z; in_t[(kc4*4+3)*INPAD + row] = v.w;
    }
    #pragma unroll
    for (int it = 0; it < 4; ++it) {
        int g = it * 256 + t;
        int kc = (g >> 8) * 4 + (g & 3);
        int row = (g >> 2) & 63;
        float4 w = *reinterpret_cast<const float4*>(W + row * D + kc * 4);
        w_t[(kc*4+0)*PAD + row] = w.x; w_t[(kc*4+1)*PAD + row] = w.y;
        w_t[(kc*4+2)*PAD + row] = w.z; w_t[(kc*4+3)*PAD + row] = w.w;
    }
    __syncthreads();

    int cg = t & 15, rg = t >> 4;
    float acc[2][4];
    #pragma unroll
    for (int i = 0; i < 2; ++i)
        #pragma unroll
        for (int j = 0; j < 4; ++j) acc[i][j] = 0.f;

    #pragma unroll 8
    for (int k = 0; k < 64; ++k) {
        float2 a2 = *reinterpret_cast<const float2*>(&in_t[k * INPAD + rg * 2]);
        float4 w4 = *reinterpret_cast<const float4*>(&w_t [k * PAD + cg * 4]);
        acc[0][0]=fmaf(a2.x,w4.x,acc[0][0]); acc[0][1]=fmaf(a2.x,w4.y,acc[0][1]);
        acc[0][2]=fmaf(a2.x,w4.z,acc[0][2]); acc[0][3]=fmaf(a2.x,w4.w,acc[0][3]);
        acc[1][0]=fmaf(a2.y,w4.x,acc[1][0]); acc[1][1]=fmaf(a2.y,w4.y,acc[1][1]);
        acc[1][2]=fmaf(a2.y,w4.z,acc[1][2]); acc[1][3]=fmaf(a2.y,w4.w,acc[1][3]);
    }

    float4 b4 = tp1 ? *reinterpret_cast<const float4*>(bc  + cg * 4)
                    : *reinterpret_cast<const float4*>(boc + cg * 4);

    if (tp1) {
        // tr[e][c_local]
        #pragma unroll
        for (int i = 0; i < 2; ++i) {
            tr[(cg*4+0)*TPAD + rg*2+i] = exp2f(TS * (acc[i][0] + b4.x));
            tr[(cg*4+1)*TPAD + rg*2+i] = exp2f(TS * (acc[i][1] + b4.y));
            tr[(cg*4+2)*TPAD + rg*2+i] = exp2f(TS * (acc[i][2] + b4.z));
            tr[(cg*4+3)*TPAD + rg*2+i] = exp2f(TS * (acc[i][3] + b4.w));
        }
        __syncthreads();
        int bb = r0 >> 8;            // batch index
        int cbase = r0 & 255;        // c offset within batch
        // 512 float4 outputs: [d4 0..15][cl 0..31], coalesced stores
        #pragma unroll
        for (int it = 0; it < 2; ++it) {
            int g = it * 256 + t;
            int d4 = g >> 5, cl = g & 31;
            float4 o;
            o.x = tr[(4*d4+0)*TPAD + cl];
            o.y = tr[(4*d4+1)*TPAD + cl];
            o.z = tr[(4*d4+2)*TPAD + cl];
            o.w = tr[(4*d4+3)*TPAD + cl];
            *reinterpret_cast<float4*>(esct + ((bb*16 + d4)*CP4 + cbase + cl)*4) = o;
        }
    } else {
        #pragma unroll
        for (int i = 0; i < 2; ++i) {
            float4 o;
            o.x = acc[i][0] + b4.x; o.y = acc[i][1] + b4.y;
            o.z = acc[i][2] + b4.z; o.w = acc[i][3] + b4.w;
            *reinterpret_cast<float4*>(wb + (r0 + rg*2 + i) * D + cg * 4) = o;
        }
    }
}

// ---------------------------------------------------------------------------
// attn_kernel: one block per (b, 4 q's); 256 threads, thread t <-> bank row c.
//  QUERY-SIDE PROJECTIONS FUSED: thread (wv,lane) computes e=lane outputs for
//  qi=wv: sq -> esq_lds (exp'd), oq kept in the exact register the epilogue
//  stores. q-row via wave-uniform s_load; Wq/Woq rows contiguous per thread
//  (16KB each, L2-hot across 1024 blocks). Accumulation order k=0..63 matches
//  the old proj kernel -> bit-identical values.
//  XCD-SWIZZLED blockIdx: batch b pinned to XCD b%8 (panels L2-resident).
//  4-WAY rcp pairing: sum wi/ai = N * rcp(a0*a1*a2*a3).
//  DEFERRED NORMALIZATION: context on unnormalized weights; rcp(SUM) in the
//  epilogue. Max-free softmax (scores tanh-bounded).
// ---------------------------------------------------------------------------
__global__ __launch_bounds__(256, 4) void attn_kernel(
    const float* __restrict__ query,
    const unsigned char* __restrict__ mask,
    const float* __restrict__ Wq, const float* __restrict__ Woq,
    const float* __restrict__ esct_g, const float* __restrict__ Ws,
    const float* __restrict__ wb_g,
    float* __restrict__ out, float* __restrict__ attn_out)
{
    int t = threadIdx.x;
    int c = t;
    // ---- batch->XCD swizzle: bijective on [0,1024), b%8 == p%8.
    int p = blockIdx.x;
    int b = (p & 7) + ((p >> 9) << 3);
    int qb = (p >> 3) & 63;
    int bq0 = b * LQ + qb * QT;
    int lane = t & 63, wv = t >> 6;

    __shared__ __align__(16) float esq_lds[QT][D];  // exp'd query scores
    __shared__ __align__(16) float a_lds[QT][LC];   // UNNORMALIZED attn weights
    __shared__ float part_lds[4 * QT * 64];
    __shared__ float red_s[4 * QT];

    // ---- fused q-side projections: qi = wv (wave-uniform), e = lane ----
    int qi0 = __builtin_amdgcn_readfirstlane(wv);
    const float* qp  = query + (bq0 + qi0) * D;     // wave-uniform -> s_load
    const float* wqr = Wq  + lane * D;
    const float* wor = Woq + lane * D;
    float sq = 0.f, oqv = 0.f;
    #pragma unroll
    for (int kc = 0; kc < 16; ++kc) {
        float4 wq4 = *reinterpret_cast<const float4*>(wqr + kc * 4);
        float4 wo4 = *reinterpret_cast<const float4*>(wor + kc * 4);
        float q0 = qp[kc*4+0], q1 = qp[kc*4+1], q2 = qp[kc*4+2], q3 = qp[kc*4+3];
        sq  = fmaf(wq4.x, q0, sq);  sq  = fmaf(wq4.y, q1, sq);
        sq  = fmaf(wq4.z, q2, sq);  sq  = fmaf(wq4.w, q3, sq);
        oqv = fmaf(wo4.x, q0, oqv); oqv = fmaf(wo4.y, q1, oqv);
        oqv = fmaf(wo4.z, q2, oqv); oqv = fmaf(wo4.w, q3, oqv);
    }
    esq_lds[qi0][lane] = exp2f(TS * sq);

    // prefetch mask bytes (coalesced)
    unsigned char mb[QT];
    #pragma unroll
    for (int qi = 0; qi < QT; ++qi) mb[qi] = mask[(bq0 + qi) * LC + c];

    __syncthreads();

    const float4* ep4 = reinterpret_cast<const float4*>(esct_g) + b*16*CP4 + c;

    float s[QT];
    #pragma unroll
    for (int qi = 0; qi < QT; ++qi) s[qi] = 0.f;

    // ---- score: 4 chunks of 16 d's; 4 float4 panel loads per chunk;
    //      esq via wave-uniform ds_read_b128 broadcast, Ws via s_load;
    //      4-way-paired rcp body ----
    #pragma unroll
    for (int kb = 0; kb < 4; ++kb) {
        float4 ec4[4];
        #pragma unroll
        for (int j = 0; j < 4; ++j) ec4[j] = ep4[(kb*4 + j) * CP4];
        #pragma unroll
        for (int j = 0; j < 4; ++j) {
            const int d0 = kb * 16 + j * 4;
            float w0 = Ws[d0+0], w1 = Ws[d0+1];
            float w2 = Ws[d0+2], w3 = Ws[d0+3];
            #pragma unroll
            for (int qi = 0; qi < QT; ++qi) {
                float4 e4 = *reinterpret_cast<const float4*>(&esq_lds[qi][d0]);
                float ax = fmaf(ec4[j].x, e4.x, 1.0f);
                float ay = fmaf(ec4[j].y, e4.y, 1.0f);
                float az = fmaf(ec4[j].z, e4.z, 1.0f);
                float aw = fmaf(ec4[j].w, e4.w, 1.0f);
                float pxy = ax * ay, pzw = az * aw;
                float nxy = fmaf(w0, ay, w1 * ax);
                float nzw = fmaf(w2, aw, w3 * az);
                float N   = fmaf(nxy, pzw, nzw * pxy);
                s[qi] = fmaf(N, __builtin_amdgcn_rcpf(pxy * pzw), s[qi]);
            }
        }
    }

    // unnormalized weights: tanh-bounded scores -> no max-subtraction needed
    float a[QT];
    #pragma unroll
    for (int qi = 0; qi < QT; ++qi) {
        a[qi] = mb[qi] ? 0.0f : exp2f(-TS * s[qi]);
    }

    // stage UNNORMALIZED weights for context; SUM reduce shares the barrier
    #pragma unroll
    for (int qi = 0; qi < QT; ++qi) a_lds[qi][c] = a[qi];
    #pragma unroll
    for (int qi = 0; qi < QT; ++qi) {
        float ss = a[qi];
        #pragma unroll
        for (int o = 32; o > 0; o >>= 1) ss += __shfl_xor(ss, o);
        if (lane == 0) red_s[wv * QT + qi] = ss;
    }
    __syncthreads();

    float rs[QT];
    #pragma unroll
    for (int qi = 0; qi < QT; ++qi) {
        float SUM = (red_s[qi] + red_s[QT + qi]) + (red_s[2*QT + qi] + red_s[3*QT + qi]);
        rs[qi] = __builtin_amdgcn_rcpf(SUM);
    }

    // normalized attention output (terminal stores, off critical path)
    #pragma unroll
    for (int qi = 0; qi < QT; ++qi)
        attn_out[(bq0 + qi) * LC + c] = a[qi] * rs[qi];

    // ---- fused context+output-proj on UNNORMALIZED weights; wave g owns
    //      c=g*64..+63; a_lds read as wave-uniform ds_read_b128 broadcasts ----
    {
        int g = wv;
        float acc[QT];
        #pragma unroll
        for (int qi = 0; qi < QT; ++qi) acc[qi] = 0.f;
        const float* wbp = wb_g + (b * LC + g * 64) * D + lane;
        #pragma unroll
        for (int i0 = 0; i0 < 64; i0 += 4) {
            float4 A0 = *reinterpret_cast<const float4*>(&a_lds[0][g*64 + i0]);
            float4 A1 = *reinterpret_cast<const float4*>(&a_lds[1][g*64 + i0]);
            float4 A2 = *reinterpret_cast<const float4*>(&a_lds[2][g*64 + i0]);
            float4 A3 = *reinterpret_cast<const float4*>(&a_lds[3][g*64 + i0]);
            float w0 = wbp[(i0+0) * D];
            float w1 = wbp[(i0+1) * D];
            float w2 = wbp[(i0+2) * D];
            float w3 = wbp[(i0+3) * D];
            acc[0] = fmaf(A0.x, w0, acc[0]); acc[1] = fmaf(A1.x, w0, acc[1]);
            acc[2] = fmaf(A2.x, w0, acc[2]); acc[3] = fmaf(A3.x, w0, acc[3]);
            acc[0] = fmaf(A0.y, w1, acc[0]); acc[1] = fmaf(A1.y, w1, acc[1]);
            acc[2] = fmaf(A2.y, w1, acc[2]); acc[3] = fmaf(A3.y, w1, acc[3]);
            acc[0] = fmaf(A0.z, w2, acc[0]); acc[1] = fmaf(A1.z, w2, acc[1]);
            acc[2] = fmaf(A2.z, w2, acc[2]); acc[3] = fmaf(A3.z, w2, acc[3]);
            acc[0] = fmaf(A0.w, w3, acc[0]); acc[1] = fmaf(A1.w, w3, acc[1]);
            acc[2] = fmaf(A2.w, w3, acc[2]); acc[3] = fmaf(A3.w, w3, acc[3]);
        }
        #pragma unroll
        for (int qi = 0; qi < QT; ++qi)
            part_lds[(g * QT + qi) * 64 + lane] = acc[qi];
    }
    __syncthreads();

    {
        int qi = t >> 6, e = t & 63;
        float ps = (part_lds[(0 * QT + qi) * 64 + e] + part_lds[(1 * QT + qi) * 64 + e])
                 + (part_lds[(2 * QT + qi) * 64 + e] + part_lds[(3 * QT + qi) * 64 + e]);
        out[bq0 * D + t] = fmaf(ps, rs[qi], oqv);
    }
}

extern "C" void kernel_launch(void* const* d_in, const int* in_sizes, int n_in,
                              void* d_out, int out_size, void* d_ws, size_t ws_size,
                              hipStream_t stream) {
    const float* query = (const float*)d_in[0];
    const float* bank  = (const float*)d_in[1];
    const unsigned char* mask = (const unsigned char*)d_in[2];
    const float* Wq  = (const float*)d_in[3];
    const float* Wc  = (const float*)d_in[4];
    const float* bc  = (const float*)d_in[5];
    const float* Ws  = (const float*)d_in[6];
    // d_in[7] = bs: row-constant, cancels in softmax
    const float* Woq = (const float*)d_in[8];
    const float* Woc = (const float*)d_in[9];
    const float* boc = (const float*)d_in[10];

    float* out  = (float*)d_out;             // [B,LQ,D]
    float* attn = out + B * LQ * D;          // [B,LQ,LC]

    float* esct = (float*)d_ws;              // [B][16 d4][CP4] float4-interleaved
    float* wb   = esct + B * 16 * CP4 * 4;   // [B*LC, D]

    bank_proj_kernel<<<256, 256, 0, stream>>>(bank, Wc, bc, Woc, boc, esct, wb);
    attn_kernel<<<B * LQ / QT, 256, 0, stream>>>(query, mask, Wq, Woq, esct, Ws,
                                                 wb, out, attn);
}

// Round 6
// 22.294 us; speedup vs baseline: 1.5455x; 1.5455x over previous
//
#include <hip/hip_runtime.h>
#include <math.h>

#define B  16
#define LQ 256
#define LC 256
#define D  64
#define QT 4
#define TS   2.88539008177793f    // 2*log2(e)
#define L2E  1.44269504088896f    // log2(e)
#define PAD  72                   // LDS row stride (floats) for w_t [k][64]
#define INPAD 36                  // LDS row stride for in_t [k][32]
#define TPAD 33                   // LDS row stride for transpose tile [e][32]
#define CP4  264                  // esct pitch in float4 units (4224B, non-pow2)

// ---------------------------------------------------------------------------
// proj_kernel: 32x64x64 GEMM per block (512 blocks = 4 types x 128 row-blocks)
//  (R2/R4-proven LDS version. R3's LDS-free and R5's fused-row variants both
//   regressed: scalar-streaming/lgkmcnt serialization and 256B-stride lane
//   gathers respectively. Weights MUST go through coalesced load + LDS.)
//   tp 0: esq [r,e]     = exp2(TS * (Wq[e,:] . query[r,:]))          row-major
//   tp 1: esct4[b,d4,c] = float4(exp2(TS*(Wc[4d4+j,:].bank[b,c,:]+bc)), j=0..3)
//   tp 2: oq  [r,e]     = Woq[e,:] . query[r,:]                      row-major
//   tp 3: wb  [r,e]     = Woc[e,:] . bank[r,:] + boc[e]              row-major
//  XCD-ALIGNED row-chunk remap: chunk for batch bb is assigned to a block id
//  with id%8 == bb%8, matching attn_kernel's batch->XCD pin.
// ---------------------------------------------------------------------------
__global__ __launch_bounds__(256) void proj_kernel(
    const float* __restrict__ query, const float* __restrict__ bank,
    const float* __restrict__ Wq, const float* __restrict__ Wc,
    const float* __restrict__ bc,
    const float* __restrict__ Woq, const float* __restrict__ Woc,
    const float* __restrict__ boc,
    float* __restrict__ esq, float* __restrict__ esct,
    float* __restrict__ oq, float* __restrict__ wb)
{
    int t  = threadIdx.x;
    int tp = blockIdx.x >> 7;
    int rb = blockIdx.x & 127;
    // batch-aligned remap: bb = (rb&7)+8*(rb>>6) in [0,16), j = (rb>>3)&7
    int bb_x = (rb & 7) + ((rb >> 6) << 3);
    int jj   = (rb >> 3) & 7;
    int r0 = bb_x * 256 + jj * 32;

    __shared__ __align__(16) float in_t[64 * INPAD]; // [k][32]
    __shared__ __align__(16) float w_t [64 * PAD];   // [k][64]
    __shared__ float tr[64 * TPAD];                  // [e][32], tp==1 only

    const float* src = (tp & 1) ? bank : query;      // tp 1,3 -> bank
    const float* W   = (tp == 0) ? Wq : (tp == 1) ? Wc : (tp == 2) ? Woq : Woc;

    #pragma unroll
    for (int it = 0; it < 2; ++it) {
        int g = it * 256 + t;
        int kc4 = g & 15, row = g >> 4;              // row 0..31
        float4 v = *reinterpret_cast<const float4*>(src + (r0 + row) * D + kc4 * 4);
        in_t[(kc4*4+0)*INPAD + row] = v.x; in_t[(kc4*4+1)*INPAD + row] = v.y;
        in_t[(kc4*4+2)*INPAD + row] = v.z; in_t[(kc4*4+3)*INPAD + row] = v.w;
    }
    #pragma unroll
    for (int it = 0; it < 4; ++it) {
        int g = it * 256 + t;
        int kc = (g >> 8) * 4 + (g & 3);
        int row = (g >> 2) & 63;
        float4 w = *reinterpret_cast<const float4*>(W + row * D + kc * 4);
        w_t[(kc*4+0)*PAD + row] = w.x; w_t[(kc*4+1)*PAD + row] = w.y;
        w_t[(kc*4+2)*PAD + row] = w.z; w_t[(kc*4+3)*PAD + row] = w.w;
    }
    __syncthreads();

    int cg = t & 15, rg = t >> 4;
    float acc[2][4];
    #pragma unroll
    for (int i = 0; i < 2; ++i)
        #pragma unroll
        for (int j = 0; j < 4; ++j) acc[i][j] = 0.f;

    #pragma unroll 8
    for (int k = 0; k < 64; ++k) {
        float2 a2 = *reinterpret_cast<const float2*>(&in_t[k * INPAD + rg * 2]);
        float4 w4 = *reinterpret_cast<const float4*>(&w_t [k * PAD + cg * 4]);
        acc[0][0]=fmaf(a2.x,w4.x,acc[0][0]); acc[0][1]=fmaf(a2.x,w4.y,acc[0][1]);
        acc[0][2]=fmaf(a2.x,w4.z,acc[0][2]); acc[0][3]=fmaf(a2.x,w4.w,acc[0][3]);
        acc[1][0]=fmaf(a2.y,w4.x,acc[1][0]); acc[1][1]=fmaf(a2.y,w4.y,acc[1][1]);
        acc[1][2]=fmaf(a2.y,w4.z,acc[1][2]); acc[1][3]=fmaf(a2.y,w4.w,acc[1][3]);
    }

    float4 b4 = {0.f, 0.f, 0.f, 0.f};
    if (tp == 1) b4 = *reinterpret_cast<const float4*>(bc  + cg * 4);
    if (tp == 3) b4 = *reinterpret_cast<const float4*>(boc + cg * 4);

    if (tp == 1) {
        // tr[e][c_local]
        #pragma unroll
        for (int i = 0; i < 2; ++i) {
            tr[(cg*4+0)*TPAD + rg*2+i] = exp2f(TS * (acc[i][0] + b4.x));
            tr[(cg*4+1)*TPAD + rg*2+i] = exp2f(TS * (acc[i][1] + b4.y));
            tr[(cg*4+2)*TPAD + rg*2+i] = exp2f(TS * (acc[i][2] + b4.z));
            tr[(cg*4+3)*TPAD + rg*2+i] = exp2f(TS * (acc[i][3] + b4.w));
        }
        __syncthreads();
        int bb = r0 >> 8;            // batch index
        int cbase = r0 & 255;        // c offset within batch
        // 512 float4 outputs: [d4 0..15][cl 0..31], coalesced stores
        #pragma unroll
        for (int it = 0; it < 2; ++it) {
            int g = it * 256 + t;
            int d4 = g >> 5, cl = g & 31;
            float4 o;
            o.x = tr[(4*d4+0)*TPAD + cl];
            o.y = tr[(4*d4+1)*TPAD + cl];
            o.z = tr[(4*d4+2)*TPAD + cl];
            o.w = tr[(4*d4+3)*TPAD + cl];
            *reinterpret_cast<float4*>(esct + ((bb*16 + d4)*CP4 + cbase + cl)*4) = o;
        }
    } else {
        float* dst = (tp == 0) ? esq : (tp == 2) ? oq : wb;
        #pragma unroll
        for (int i = 0; i < 2; ++i) {
            float4 o;
            o.x = acc[i][0] + b4.x; o.y = acc[i][1] + b4.y;
            o.z = acc[i][2] + b4.z; o.w = acc[i][3] + b4.w;
            if (tp == 0) {
                o.x = exp2f(TS * o.x); o.y = exp2f(TS * o.y);
                o.z = exp2f(TS * o.z); o.w = exp2f(TS * o.w);
            }
            *reinterpret_cast<float4*>(dst + (r0 + rg*2 + i) * D + cg * 4) = o;
        }
    }
}

// ---------------------------------------------------------------------------
// attn_kernel: one block per (b, 4 q's); 256 threads, thread t <-> bank row c.
//  XCD-SWIZZLED blockIdx: batch b pinned to XCD b%8 (panels L2-resident).
//  ESQ VIA LDS BROADCAST (this round's single change vs R4): the 256
//  block-uniform esq floats exceed the SGPR file, so the SMEM path had to
//  stream s_load chunks with lgkmcnt serialization through the score loop.
//  Now: one coalesced 1KB global read -> esq_lds; score reads wave-uniform
//  ds_read_b128 broadcasts landing in plentiful VGPRs. Ws (64 floats) stays
//  on the scalar path (fits SGPRs).
//  4-WAY rcp pairing: w0/a0+w1/a1+w2/a2+w3/a3 = N * rcp(a0*a1*a2*a3).
//  DEFERRED NORMALIZATION: context on unnormalized weights; rcp(SUM) in the
//  epilogue. Max-free softmax (scores tanh-bounded).
// ---------------------------------------------------------------------------
__global__ __launch_bounds__(256, 4) void attn_kernel(
    const unsigned char* __restrict__ mask,
    const float* __restrict__ esq_g, const float* __restrict__ esct_g,
    const float* __restrict__ Ws,
    const float* __restrict__ oq_g, const float* __restrict__ wb_g,
    float* __restrict__ out, float* __restrict__ attn_out)
{
    int t = threadIdx.x;
    int c = t;
    // ---- batch->XCD swizzle: bijective on [0,1024), b%8 == p%8.
    int p = blockIdx.x;
    int b = (p & 7) + ((p >> 9) << 3);
    int qb = (p >> 3) & 63;
    int bq0 = b * LQ + qb * QT;
    int lane = t & 63, wv = t >> 6;

    __shared__ __align__(16) float esq_lds[QT][D];  // exp'd query scores
    __shared__ __align__(16) float a_lds[QT][LC];   // UNNORMALIZED attn weights
    __shared__ float part_lds[4 * QT * 64];
    __shared__ float red_s[4 * QT];

    // ---- stage esq: one coalesced 1KB read (4 rows x 64 = 1 float/thread)
    esq_lds[t >> 6][t & 63] = esq_g[bq0 * D + t];

    // prefetch mask bytes (coalesced)
    unsigned char mb[QT];
    #pragma unroll
    for (int qi = 0; qi < QT; ++qi) mb[qi] = mask[(bq0 + qi) * LC + c];

    __syncthreads();

    const float4* ep4 = reinterpret_cast<const float4*>(esct_g) + b*16*CP4 + c;

    float s[QT];
    #pragma unroll
    for (int qi = 0; qi < QT; ++qi) s[qi] = 0.f;

    // ---- score: 4 chunks of 16 d's; 4 float4 panel loads per chunk;
    //      esq via wave-uniform ds_read_b128 broadcast, Ws via s_load;
    //      4-way-paired rcp body ----
    #pragma unroll
    for (int kb = 0; kb < 4; ++kb) {
        float4 ec4[4];
        #pragma unroll
        for (int j = 0; j < 4; ++j) ec4[j] = ep4[(kb*4 + j) * CP4];
        #pragma unroll
        for (int j = 0; j < 4; ++j) {
            const int d0 = kb * 16 + j * 4;
            float w0 = Ws[d0+0], w1 = Ws[d0+1];
            float w2 = Ws[d0+2], w3 = Ws[d0+3];
            #pragma unroll
            for (int qi = 0; qi < QT; ++qi) {
                float4 e4 = *reinterpret_cast<const float4*>(&esq_lds[qi][d0]);
                float ax = fmaf(ec4[j].x, e4.x, 1.0f);
                float ay = fmaf(ec4[j].y, e4.y, 1.0f);
                float az = fmaf(ec4[j].z, e4.z, 1.0f);
                float aw = fmaf(ec4[j].w, e4.w, 1.0f);
                float pxy = ax * ay, pzw = az * aw;
                float nxy = fmaf(w0, ay, w1 * ax);
                float nzw = fmaf(w2, aw, w3 * az);
                float N   = fmaf(nxy, pzw, nzw * pxy);
                s[qi] = fmaf(N, __builtin_amdgcn_rcpf(pxy * pzw), s[qi]);
            }
        }
    }

    // unnormalized weights: tanh-bounded scores -> no max-subtraction needed
    float a[QT];
    #pragma unroll
    for (int qi = 0; qi < QT; ++qi) {
        a[qi] = mb[qi] ? 0.0f : exp2f(-TS * s[qi]);
    }

    // stage UNNORMALIZED weights for context; SUM reduce shares the barrier
    #pragma unroll
    for (int qi = 0; qi < QT; ++qi) a_lds[qi][c] = a[qi];
    #pragma unroll
    for (int qi = 0; qi < QT; ++qi) {
        float ss = a[qi];
        #pragma unroll
        for (int o = 32; o > 0; o >>= 1) ss += __shfl_xor(ss, o);
        if (lane == 0) red_s[wv * QT + qi] = ss;
    }
    __syncthreads();

    float rs[QT];
    #pragma unroll
    for (int qi = 0; qi < QT; ++qi) {
        float SUM = (red_s[qi] + red_s[QT + qi]) + (red_s[2*QT + qi] + red_s[3*QT + qi]);
        rs[qi] = __builtin_amdgcn_rcpf(SUM);
    }

    // normalized attention output (terminal stores, off critical path)
    #pragma unroll
    for (int qi = 0; qi < QT; ++qi)
        attn_out[(bq0 + qi) * LC + c] = a[qi] * rs[qi];

    // ---- fused context+output-proj on UNNORMALIZED weights; wave g owns
    //      c=g*64..+63; a_lds read as wave-uniform ds_read_b128 broadcasts ----
    {
        int g = wv;
        float acc[QT];
        #pragma unroll
        for (int qi = 0; qi < QT; ++qi) acc[qi] = 0.f;
        const float* wbp = wb_g + (b * LC + g * 64) * D + lane;
        #pragma unroll
        for (int i0 = 0; i0 < 64; i0 += 4) {
            float4 A0 = *reinterpret_cast<const float4*>(&a_lds[0][g*64 + i0]);
            float4 A1 = *reinterpret_cast<const float4*>(&a_lds[1][g*64 + i0]);
            float4 A2 = *reinterpret_cast<const float4*>(&a_lds[2][g*64 + i0]);
            float4 A3 = *reinterpret_cast<const float4*>(&a_lds[3][g*64 + i0]);
            float w0 = wbp[(i0+0) * D];
            float w1 = wbp[(i0+1) * D];
            float w2 = wbp[(i0+2) * D];
            float w3 = wbp[(i0+3) * D];
            acc[0] = fmaf(A0.x, w0, acc[0]); acc[1] = fmaf(A1.x, w0, acc[1]);
            acc[2] = fmaf(A2.x, w0, acc[2]); acc[3] = fmaf(A3.x, w0, acc[3]);
            acc[0] = fmaf(A0.y, w1, acc[0]); acc[1] = fmaf(A1.y, w1, acc[1]);
            acc[2] = fmaf(A2.y, w1, acc[2]); acc[3] = fmaf(A3.y, w1, acc[3]);
            acc[0] = fmaf(A0.z, w2, acc[0]); acc[1] = fmaf(A1.z, w2, acc[1]);
            acc[2] = fmaf(A2.z, w2, acc[2]); acc[3] = fmaf(A3.z, w2, acc[3]);
            acc[0] = fmaf(A0.w, w3, acc[0]); acc[1] = fmaf(A1.w, w3, acc[1]);
            acc[2] = fmaf(A2.w, w3, acc[2]); acc[3] = fmaf(A3.w, w3, acc[3]);
        }
        #pragma unroll
        for (int qi = 0; qi < QT; ++qi)
            part_lds[(g * QT + qi) * 64 + lane] = acc[qi];
    }
    __syncthreads();

    {
        int qi = t >> 6, e = t & 63;
        float ps = (part_lds[(0 * QT + qi) * 64 + e] + part_lds[(1 * QT + qi) * 64 + e])
                 + (part_lds[(2 * QT + qi) * 64 + e] + part_lds[(3 * QT + qi) * 64 + e]);
        out[bq0 * D + t] = fmaf(ps, rs[qi], oq_g[bq0 * D + t]);
    }
}

extern "C" void kernel_launch(void* const* d_in, const int* in_sizes, int n_in,
                              void* d_out, int out_size, void* d_ws, size_t ws_size,
                              hipStream_t stream) {
    const float* query = (const float*)d_in[0];
    const float* bank  = (const float*)d_in[1];
    const unsigned char* mask = (const unsigned char*)d_in[2];
    const float* Wq  = (const float*)d_in[3];
    const float* Wc  = (const float*)d_in[4];
    const float* bc  = (const float*)d_in[5];
    const float* Ws  = (const float*)d_in[6];
    // d_in[7] = bs: row-constant, cancels in softmax
    const float* Woq = (const float*)d_in[8];
    const float* Woc = (const float*)d_in[9];
    const float* boc = (const float*)d_in[10];

    float* out  = (float*)d_out;             // [B,LQ,D]
    float* attn = out + B * LQ * D;          // [B,LQ,LC]

    float* esq  = (float*)d_ws;              // [B*LQ, D]
    float* esct = esq + B * LQ * D;          // [B][16 d4][CP4] float4-interleaved
    float* oq   = esct + B * 16 * CP4 * 4;   // [B*LQ, D]
    float* wb   = oq + B * LQ * D;           // [B*LC, D]

    proj_kernel<<<4 * 128, 256, 0, stream>>>(query, bank, Wq, Wc, bc,
                                             Woq, Woc, boc,
                                             esq, esct, oq, wb);
    attn_kernel<<<B * LQ / QT, 256, 0, stream>>>(mask, esq, esct, Ws,
                                                 oq, wb, out, attn);
}